// Round 8
// baseline (208.205 us; speedup 1.0000x reference)
//
#include <hip/hip_runtime.h>
#include <hip/hip_bf16.h>
#include <cstdint>
#include <cstddef>

typedef __attribute__((ext_vector_type(8))) short bf16x8;
typedef __attribute__((ext_vector_type(4))) float f32x4;
typedef __attribute__((address_space(3))) void lds_void;
typedef const __attribute__((address_space(1))) void g_void;

constexpr int Bc = 2, Sc = 2048, Dc = 512, Hc = 8, DKc = 64;
constexpr int SPLIT = 2;
constexpr int NKT = Sc / 64;           // 32 k-tiles total
constexpr int KT_PER = NKT / SPLIT;    // 16 per block
constexpr float CSC = 0.18033688011112042f;  // 0.125 * log2(e), folded into Q projection

struct alignas(16) us8 { unsigned short u[8]; };
struct alignas(8) us4 { unsigned short u[4]; };

__device__ __forceinline__ unsigned short f2bf(float x) {
  union { float f; unsigned int u; } v; v.f = x;
  unsigned int r = (v.u + 0x7FFFu + ((v.u >> 16) & 1u)) >> 16;
  return (unsigned short)r;
}

__device__ __forceinline__ float bf2f(unsigned short u) {
  union { unsigned int u; float f; } v; v.u = ((unsigned int)u) << 16;
  return v.f;
}

__device__ __forceinline__ us8 cvt8(float4 a, float4 b) {
  us8 o;
  o.u[0] = f2bf(a.x); o.u[1] = f2bf(a.y); o.u[2] = f2bf(a.z); o.u[3] = f2bf(a.w);
  o.u[4] = f2bf(b.x); o.u[5] = f2bf(b.y); o.u[6] = f2bf(b.z); o.u[7] = f2bf(b.w);
  return o;
}

// ---------------- prepass: 7 fp32->bf16 conversions in one launch ----------------
struct CArgs { const float* src[7]; unsigned short* dst[7]; int n8[7]; };

__global__ __launch_bounds__(256)
void cvt_multi(CArgs a)
{
  const int y = blockIdx.y;
  const float* s = a.src[y];
  unsigned short* d = a.dst[y];
  const int n8 = a.n8[y];
  int i = blockIdx.x * blockDim.x + threadIdx.x;
  const int stride = gridDim.x * blockDim.x;
  for (; i < n8; i += stride) {
    float4 va = ((const float4*)s)[(size_t)i * 2];
    float4 vb = ((const float4*)s)[(size_t)i * 2 + 1];
    ((us8*)d)[i] = cvt8(va, vb);
  }
}

// ---------------- prepass: g_eff = bf16(g * (mask|diag)) + packed mask bits ----------------
__global__ __launch_bounds__(256)
void cvt_gmask(const float* __restrict__ g, const int* __restrict__ m,
               unsigned short* __restrict__ ge, unsigned long long* __restrict__ mb,
               int ngr8)
{
  const int lane = threadIdx.x & 63;
  int i = blockIdx.x * blockDim.x + threadIdx.x;    // 8-element group index
  const int stride = gridDim.x * blockDim.x;
  for (; i < ngr8; i += stride) {
    const size_t base = (size_t)i * 8;
    const int rem = (int)(base & ((size_t)Sc * Sc - 1));
    const int row = rem >> 11;
    const int col0 = rem & (Sc - 1);
    int4 m0 = *(const int4*)(m + base);
    int4 m1 = *(const int4*)(m + base + 4);
    float4 g0 = *(const float4*)(g + base);
    float4 g1 = *(const float4*)(g + base + 4);
    const int mm[8] = {m0.x, m0.y, m0.z, m0.w, m1.x, m1.y, m1.z, m1.w};
    const float gg[8] = {g0.x, g0.y, g0.z, g0.w, g1.x, g1.y, g1.z, g1.w};
    us8 o; unsigned int pm = 0;
#pragma unroll
    for (int j = 0; j < 8; ++j) {
      const bool pred = (mm[j] != 0) || (col0 + j == row);
      o.u[j] = pred ? f2bf(gg[j]) : (unsigned short)0;
      pm |= (pred ? 1u : 0u) << j;
    }
    ((us8*)ge)[i] = o;
    unsigned long long v = (unsigned long long)pm << ((lane & 7) * 8);
    v |= __shfl_xor(v, 1);
    v |= __shfl_xor(v, 2);
    v |= __shfl_xor(v, 4);
    if ((lane & 7) == 0) mb[i >> 3] = v;
  }
}

// ---------------- 128x128-tile bf16 NT GEMM (m97 structure) ----------------
struct GArgs {
  const unsigned short* A[3];
  const unsigned short* W[3];
  const float* bias[3];
  void* C[3];
  int mode[3];
  float osc[3];      // output scale (mode 0 only)
};

__global__ __launch_bounds__(256)
void gemm128(GArgs ga)
{
  __shared__ unsigned short As[128][64];   // XOR-swizzled rows (128 B, 8 slots)
  __shared__ unsigned short Bs[128][64];

  constexpr int K = 512, N = 512;
  const int z = blockIdx.z;
  const unsigned short* Ap = ga.A[z];
  const unsigned short* Wp = ga.W[z];
  const float* bias = ga.bias[z];
  const int mode = ga.mode[z];
  const float osc = ga.osc[z];

  const int tid = threadIdx.x, lane = tid & 63, w = tid >> 6;
  const int m0 = blockIdx.x * 128, n0 = blockIdx.y * 128;
  const int wm = w >> 1, wn = w & 1;
  const int colb = lane & 15, hi = lane >> 4, rowb = hi * 4;
  const int swz = (colb & 7) << 4;

  f32x4 acc[4][4];
#pragma unroll
  for (int i = 0; i < 4; ++i)
#pragma unroll
    for (int j = 0; j < 4; ++j) acc[i][j] = (f32x4){0.f, 0.f, 0.f, 0.f};

  const int lrow8 = lane >> 3;
  const int cb = ((lane & 7) * 16) ^ (lrow8 << 4);

  for (int k0 = 0; k0 < K; k0 += 64) {
    if (k0) __syncthreads();
#pragma unroll
    for (int i = 0; i < 4; ++i) {
      const int obase = w * 1024 + i * 4096;
      const int row = w * 8 + i * 32 + lrow8;
      const unsigned short* asrc = Ap + (size_t)(m0 + row) * K + k0 + (cb >> 1);
      const unsigned short* bsrc = Wp + (size_t)(n0 + row) * K + k0 + (cb >> 1);
      __builtin_amdgcn_global_load_lds((g_void*)asrc, (lds_void*)((char*)&As[0][0] + obase), 16, 0, 0);
      __builtin_amdgcn_global_load_lds((g_void*)bsrc, (lds_void*)((char*)&Bs[0][0] + obase), 16, 0, 0);
    }
    asm volatile("s_waitcnt vmcnt(0)" ::: "memory");
    __syncthreads();

    char* ab = (char*)&As[0][0];
    char* bb = (char*)&Bs[0][0];
#pragma unroll
    for (int kk = 0; kk < 2; ++kk) {
      bf16x8 af[4], bfr[4];
#pragma unroll
      for (int mf = 0; mf < 4; ++mf) {
        const int ar = wm * 64 + mf * 16 + colb;
        af[mf] = *(const bf16x8*)(ab + ar * 128 + ((kk * 64 + hi * 16) ^ swz));
      }
#pragma unroll
      for (int nf = 0; nf < 4; ++nf) {
        const int br = wn * 64 + nf * 16 + colb;
        bfr[nf] = *(const bf16x8*)(bb + br * 128 + ((kk * 64 + hi * 16) ^ swz));
      }
      __builtin_amdgcn_s_setprio(1);
#pragma unroll
      for (int mf = 0; mf < 4; ++mf)
#pragma unroll
        for (int nf = 0; nf < 4; ++nf)
          acc[mf][nf] = __builtin_amdgcn_mfma_f32_16x16x32_bf16(af[mf], bfr[nf], acc[mf][nf], 0, 0, 0);
      __builtin_amdgcn_s_setprio(0);
    }
  }

#pragma unroll
  for (int nf = 0; nf < 4; ++nf) {
    const int gn = n0 + wn * 64 + nf * 16 + colb;
    const float bv = bias[gn];
    if (mode == 1) {
      unsigned short* Cp = (unsigned short*)ga.C[z];
#pragma unroll
      for (int mf = 0; mf < 4; ++mf) {
        const int gm = m0 + wm * 64 + mf * 16 + rowb;
        const int bb_ = gm >> 11, ss = gm & (Sc - 1);
        us4 vv;
#pragma unroll
        for (int rr = 0; rr < 4; ++rr) vv.u[rr] = f2bf(acc[mf][nf][rr] + bv);
        *(us4*)(Cp + ((size_t)bb_ * N + gn) * Sc + ss) = vv;
      }
    } else if (mode == 0) {
      unsigned short* Cp = (unsigned short*)ga.C[z];
#pragma unroll
      for (int mf = 0; mf < 4; ++mf)
#pragma unroll
        for (int rr = 0; rr < 4; ++rr) {
          const int gm = m0 + wm * 64 + mf * 16 + rowb + rr;
          Cp[(size_t)gm * N + gn] = f2bf((acc[mf][nf][rr] + bv) * osc);
        }
    } else {
      float* Cp = (float*)ga.C[z];
#pragma unroll
      for (int mf = 0; mf < 4; ++mf)
#pragma unroll
        for (int rr = 0; rr < 4; ++rr) {
          const int gm = m0 + wm * 64 + mf * 16 + rowb + rr;
          Cp[(size_t)gm * N + gn] = acc[mf][nf][rr] + bv;
        }
    }
  }
}

// ---------------- split-K flash attention: barrier-free, K/V fragments direct from L2 ----------------
// grid (B*H, S/64, SPLIT). Partials: Pacc[blk][d=64][q=64] (O^T), Pml[blk][2][64] (m log2-domain).
// Each wave is fully independent (16 q-rows); only wave-private Ps lives in LDS.
__global__ __launch_bounds__(256, 4)
void attn_split(const unsigned short* __restrict__ Qb,
                const unsigned short* __restrict__ Kb,
                const unsigned short* __restrict__ Vt,
                const unsigned short* __restrict__ Gb,
                const unsigned long long* __restrict__ Mb,
                float* __restrict__ Pacc,
                float* __restrict__ Pml)
{
  __shared__ unsigned short Ps[4][16][64];   // per-wave P [q][k], XOR-swizzled rows

  const int tid = threadIdx.x, lane = tid & 63, wid = tid >> 6;
  const int bh = blockIdx.x, b = bh >> 3, h = bh & 7;
  const int qt = blockIdx.y, q0 = qt * 64;
  const int sp = blockIdx.z;
  const int kt0 = sp * KT_PER;

  const int colb = lane & 15;
  const int hi = lane >> 4;
  const int rowb = hi * 4;
  const int c3s = (colb & 7) << 4;

  // Q fragment (pre-scaled by CSC at projection): lane holds Q[q=wid*16+colb][d=hi*8+j]
  bf16x8 qf[2];
  {
    const unsigned short* qp = Qb + ((size_t)(b * Sc + q0 + wid * 16 + colb) * Dc + h * DKc + hi * 8);
    qf[0] = *(const bf16x8*)qp;
    qf[1] = *(const bf16x8*)(qp + 32);
  }

  f32x4 acc[4] = {{0,0,0,0},{0,0,0,0},{0,0,0,0},{0,0,0,0}};   // acc[n][rr] = O^T[n*16+rowb+rr][q]
  float mrun = -1e30f, lrun = 0.f;

  const unsigned long long* mrow = Mb + ((size_t)(b * Sc) + q0 + wid * 16 + colb) * NKT;
  const unsigned short* growb = Gb + ((size_t)(b * Sc) + q0 + wid * 16 + colb) * Sc + hi * 4;
  // fragment bases: K rows (krow = n*16+colb) at d-offset hi*8; V^T rows (d = n*16+colb) at k-offset hi*8
  const unsigned short* kbase = Kb + ((size_t)(b * Sc) + colb) * Dc + h * DKc + hi * 8;
  const unsigned short* vbase = Vt + ((size_t)(b * Dc) + h * DKc + colb) * Sc + hi * 8;

  us4 gcur[4];
  unsigned long long mcur;
  auto loadGM = [&](int kt, us4* gv, unsigned long long& mm) {
    const unsigned short* gp = growb + kt * 64;
#pragma unroll
    for (int n = 0; n < 4; ++n) gv[n] = *(const us4*)(gp + n * 16);
    mm = mrow[kt];
  };

  loadGM(kt0, gcur, mcur);

  char* psbase = (char*)&Ps[wid][0][0];

  for (int j = 0; j < KT_PER; ++j) {
    const int kt = kt0 + j;
    const int k0 = kt * 64;
    us4 gnx[4]; unsigned long long mn_;
    if (j + 1 < KT_PER) loadGM(kt + 1, gnx, mn_);

    // K fragments straight from global (L2-resident): kf[kk][n] = K[n*16+colb][kk*32+hi*8 ..]
    bf16x8 kf[2][4];
#pragma unroll
    for (int n = 0; n < 4; ++n) {
      const unsigned short* kp = kbase + (size_t)(k0 + n * 16) * Dc;
      kf[0][n] = *(const bf16x8*)kp;
      kf[1][n] = *(const bf16x8*)(kp + 32);
    }

    // S^T = K Q^T : sf[n][rr] = S[q=colb][k = n*16 + hi*4 + rr]
    f32x4 sf[4] = {{0,0,0,0},{0,0,0,0},{0,0,0,0},{0,0,0,0}};
    __builtin_amdgcn_s_setprio(1);
#pragma unroll
    for (int kk = 0; kk < 2; ++kk)
#pragma unroll
      for (int n = 0; n < 4; ++n)
        sf[n] = __builtin_amdgcn_mfma_f32_16x16x32_bf16(kf[kk][n], qf[kk], sf[n], 0, 0, 0);
    __builtin_amdgcn_s_setprio(0);

    // V fragments (issued after QK to bound VGPR; land under softmax): vf[kk][n] = V^T[n*16+colb][k0+kk*32+hi*8..]
    bf16x8 vf[2][4];
#pragma unroll
    for (int n = 0; n < 4; ++n) {
      const unsigned short* vp = vbase + (size_t)(n * 16) * Sc + k0;
      vf[0][n] = *(const bf16x8*)vp;
      vf[1][n] = *(const bf16x8*)(vp + 32);
    }

    // unmasked row max (legal: common scale cancels; gating via bitf and pre-masked g)
    float tm = sf[0][0];
#pragma unroll
    for (int n = 0; n < 4; ++n)
#pragma unroll
      for (int rr = 0; rr < 4; ++rr) tm = fmaxf(tm, sf[n][rr]);
    tm = fmaxf(tm, __shfl_xor(tm, 16));
    tm = fmaxf(tm, __shfl_xor(tm, 32));

    // defer-max: rescale only when some row grows by >8 (log2); P bounded by 2^8
    if (__any(tm > mrun + 8.f)) {
      const float mnew = fmaxf(mrun, tm);
      const float alpha = __builtin_amdgcn_exp2f(mrun - mnew);
      mrun = mnew;
#pragma unroll
      for (int n = 0; n < 4; ++n)
#pragma unroll
        for (int rr = 0; rr < 4; ++rr) acc[n][rr] *= alpha;
      lrun *= alpha;
    }

    // p = exp2(s-m); rsum gated by mask bit; pg uses pre-masked g
    const unsigned long long msh = mcur >> (hi * 4);
    const unsigned int mlo = (unsigned int)msh, mhi2 = (unsigned int)(msh >> 32);
    float rsum = 0.f;
    unsigned int pw[8];
#pragma unroll
    for (int n = 0; n < 4; ++n) {
#pragma unroll
      for (int s2 = 0; s2 < 2; ++s2) {
        const int i0 = s2 * 2, i1 = s2 * 2 + 1;
        const float p0 = __builtin_amdgcn_exp2f(sf[n][i0] - mrun);
        const float p1 = __builtin_amdgcn_exp2f(sf[n][i1] - mrun);
        const float b0 = (float)((n < 2 ? (mlo >> (n * 16 + i0)) : (mhi2 >> ((n - 2) * 16 + i0))) & 1u);
        const float b1 = (float)((n < 2 ? (mlo >> (n * 16 + i1)) : (mhi2 >> ((n - 2) * 16 + i1))) & 1u);
        rsum = fmaf(p0, b0, rsum);
        rsum = fmaf(p1, b1, rsum);
        const float q0v = p0 * bf2f(gcur[n].u[i0]), q1v = p1 * bf2f(gcur[n].u[i1]);
        asm("v_cvt_pk_bf16_f32 %0, %1, %2" : "=v"(pw[n * 2 + s2]) : "v"(q0v), "v"(q1v));
      }
    }
    rsum += __shfl_xor(rsum, 16);
    rsum += __shfl_xor(rsum, 32);
    lrun += rsum;

    // store P [q=colb][k] as 4x ds_write_b64 (wave-private; in-wave lgkm ordering suffices)
#pragma unroll
    for (int n = 0; n < 4; ++n) {
      const unsigned long long w64 = ((unsigned long long)pw[n * 2 + 1] << 32) | pw[n * 2];
      *(unsigned long long*)(psbase + colb * 128 + ((n * 32 + hi * 8) ^ c3s)) = w64;
    }

    // acc += V^T P^T  (O^T layout)
    __builtin_amdgcn_s_setprio(1);
#pragma unroll
    for (int kk = 0; kk < 2; ++kk) {
      bf16x8 pf = *(const bf16x8*)(psbase + colb * 128 + ((kk * 64 + hi * 16) ^ c3s));
#pragma unroll
      for (int n = 0; n < 4; ++n)
        acc[n] = __builtin_amdgcn_mfma_f32_16x16x32_bf16(vf[kk][n], pf, acc[n], 0, 0, 0);
    }
    __builtin_amdgcn_s_setprio(0);

    if (j + 1 < KT_PER) {
#pragma unroll
      for (int n = 0; n < 4; ++n) gcur[n] = gnx[n];
      mcur = mn_;
    }
  }

  // write partials (O^T layout: [d][q])
  const size_t blin = ((size_t)bh * 32 + qt) * SPLIT + sp;
  float* pa = Pacc + blin * 4096;
#pragma unroll
  for (int n = 0; n < 4; ++n)
#pragma unroll
    for (int rr = 0; rr < 4; ++rr)
      pa[(size_t)(n * 16 + rowb + rr) * 64 + wid * 16 + colb] = acc[n][rr];
  if (hi == 0) {
    float* pm = Pml + blin * 128;
    pm[wid * 16 + colb] = mrun;
    pm[64 + wid * 16 + colb] = lrun;
  }
}

// ---------------- recombine split partials -> bf16 X (m in log2 domain) ----------------
__global__ __launch_bounds__(256)
void attn_reduce(const float* __restrict__ Pacc, const float* __restrict__ Pml,
                 unsigned short* __restrict__ Xb)
{
  const int gidx = blockIdx.x;      // bh*32 + qt
  const int bh = gidx >> 5, qt = gidx & 31;
  const int b = bh >> 3, h = bh & 7;
  const int tid = threadIdx.x;
  const int qi = tid & 63;
  const int d0 = (tid >> 6) * 16;
  const size_t pb = (size_t)gidx * SPLIT;

  float m[SPLIT], l[SPLIT];
  float mstar = -3.0e38f;
#pragma unroll
  for (int s = 0; s < SPLIT; ++s) {
    m[s] = Pml[(pb + s) * 128 + qi];
    l[s] = Pml[(pb + s) * 128 + 64 + qi];
    mstar = fmaxf(mstar, m[s]);
  }
  float w[SPLIT], denom = 0.f;
#pragma unroll
  for (int s = 0; s < SPLIT; ++s) { w[s] = __builtin_amdgcn_exp2f(m[s] - mstar); denom += w[s] * l[s]; }
  const float inv = 1.0f / denom;

  unsigned short vals[16];
#pragma unroll
  for (int j = 0; j < 16; ++j) {
    float a = 0.f;
#pragma unroll
    for (int s = 0; s < SPLIT; ++s)
      a += w[s] * Pacc[(pb + s) * 4096 + (size_t)(d0 + j) * 64 + qi];
    vals[j] = f2bf(a * inv);
  }
  unsigned short* xp = Xb + ((size_t)(b * Sc) + qt * 64 + qi) * Dc + h * DKc + d0;
  *(us8*)xp = *(us8*)&vals[0];
  *(us8*)(xp + 8) = *(us8*)&vals[8];
}

extern "C" void kernel_launch(void* const* d_in, const int* in_sizes, int n_in,
                              void* d_out, int out_size, void* d_ws, size_t ws_size,
                              hipStream_t stream)
{
  const float* query = (const float*)d_in[0];
  const float* key_  = (const float*)d_in[1];
  const float* value = (const float*)d_in[2];
  const float* gprob = (const float*)d_in[3];
  const int*   mask  = (const int*)d_in[4];
  const float* Wq = (const float*)d_in[5];
  const float* bq = (const float*)d_in[6];
  const float* Wk = (const float*)d_in[7];
  const float* bk = (const float*)d_in[8];
  const float* Wv = (const float*)d_in[9];
  const float* bv = (const float*)d_in[10];
  const float* Wo = (const float*)d_in[11];
  const float* bo = (const float*)d_in[12];
  float* out = (float*)d_out;

  const size_t elems = (size_t)Bc * Sc * Dc;     // 2 Mi
  const size_t gelems = (size_t)Bc * Sc * Sc;    // 8 Mi
  const size_t welems = (size_t)Dc * Dc;         // 256 Ki

  char* base = (char*)d_ws;
  unsigned short* Qb = (unsigned short*)(base);                    // 4 MB
  unsigned short* Kb = Qb + elems;                                 // 4 MB
  unsigned short* Vt = Kb + elems;                                 // 4 MB
  unsigned short* Xb = Vt + elems;                                 // 4 MB
  unsigned short* Gb = Xb + elems;                                 // 16.8 MB (masked bf16 g)
  unsigned long long* Mbits = (unsigned long long*)(Gb + gelems);  // 1 MB
  char* shared_region = (char*)(Mbits + gelems / 64);
  // shared region: first bf16 copies of q/k/v inputs, later split partials
  unsigned short* Ain = (unsigned short*)shared_region;            // 4 MB
  unsigned short* Bin = Ain + elems;                               // 4 MB
  unsigned short* Cin = Bin + elems;                               // 4 MB
  float* Pacc = (float*)shared_region;                             // 16.8 MB
  float* Pml  = Pacc + (size_t)(Bc * Hc) * 32 * SPLIT * 4096;      // 0.5 MB
  // weights (bf16) past the shared region's max extent
  unsigned short* Wqb = (unsigned short*)(shared_region + (18u << 20));
  unsigned short* Wkb = Wqb + welems;
  unsigned short* Wvb = Wkb + welems;
  unsigned short* Wob = Wvb + welems;

  // prepasses
  CArgs ca;
  ca.src[0] = query; ca.dst[0] = Ain; ca.n8[0] = (int)(elems / 8);
  ca.src[1] = key_;  ca.dst[1] = Bin; ca.n8[1] = (int)(elems / 8);
  ca.src[2] = value; ca.dst[2] = Cin; ca.n8[2] = (int)(elems / 8);
  ca.src[3] = Wq;    ca.dst[3] = Wqb; ca.n8[3] = (int)(welems / 8);
  ca.src[4] = Wk;    ca.dst[4] = Wkb; ca.n8[4] = (int)(welems / 8);
  ca.src[5] = Wv;    ca.dst[5] = Wvb; ca.n8[5] = (int)(welems / 8);
  ca.src[6] = Wo;    ca.dst[6] = Wob; ca.n8[6] = (int)(welems / 8);
  hipLaunchKernelGGL(cvt_multi, dim3(128, 7), dim3(256), 0, stream, ca);
  hipLaunchKernelGGL(cvt_gmask, dim3(2048), dim3(256), 0, stream, gprob, mask, Gb, Mbits, (int)(gelems / 8));

  // fused Q/K/V projections (Q output pre-scaled by CSC)
  GArgs gq;
  gq.A[0] = Ain; gq.W[0] = Wqb; gq.bias[0] = bq; gq.C[0] = (void*)Qb; gq.mode[0] = 0; gq.osc[0] = CSC;
  gq.A[1] = Bin; gq.W[1] = Wkb; gq.bias[1] = bk; gq.C[1] = (void*)Kb; gq.mode[1] = 0; gq.osc[1] = 1.0f;
  gq.A[2] = Cin; gq.W[2] = Wvb; gq.bias[2] = bv; gq.C[2] = (void*)Vt; gq.mode[2] = 1; gq.osc[2] = 1.0f;
  hipLaunchKernelGGL(gemm128, dim3(32, 4, 3), dim3(256), 0, stream, gq);

  dim3 ga(Bc * Hc, Sc / 64, SPLIT);
  hipLaunchKernelGGL(attn_split, ga, dim3(256), 0, stream, Qb, Kb, Vt, Gb, Mbits, Pacc, Pml);
  hipLaunchKernelGGL(attn_reduce, dim3(Bc * Hc * 32), dim3(256), 0, stream, Pacc, Pml, Xb);

  // output projection
  GArgs go;
  go.A[0] = Xb; go.W[0] = Wob; go.bias[0] = bo; go.C[0] = (void*)out; go.mode[0] = 2; go.osc[0] = 1.0f;
  go.A[1] = Xb; go.W[1] = Wob; go.bias[1] = bo; go.C[1] = (void*)out; go.mode[1] = 2; go.osc[1] = 1.0f;
  go.A[2] = Xb; go.W[2] = Wob; go.bias[2] = bo; go.C[2] = (void*)out; go.mode[2] = 2; go.osc[2] = 1.0f;
  hipLaunchKernelGGL(gemm128, dim3(32, 4, 1), dim3(256), 0, stream, go);
}

// Round 9
// 102.897 us; speedup vs baseline: 2.0234x; 2.0234x over previous
//
#include <hip/hip_runtime.h>
#include <hip/hip_bf16.h>
#include <cstdint>
#include <cstddef>

typedef __attribute__((ext_vector_type(8))) short bf16x8;
typedef __attribute__((ext_vector_type(4))) float f32x4;
typedef __attribute__((address_space(3))) void lds_void;
typedef const __attribute__((address_space(1))) void g_void;

constexpr int Bc = 2, Sc = 2048, Dc = 512, Hc = 8, DKc = 64;
constexpr int SPLIT = 2;
constexpr int NKT = Sc / 64;           // 32 k-tiles total
constexpr int KT_PER = NKT / SPLIT;    // 16 per block
constexpr float CSC = 0.18033688011112042f;  // 0.125 * log2(e), folded into Q projection

struct alignas(16) us8 { unsigned short u[8]; };
struct alignas(8) us4 { unsigned short u[4]; };

__device__ __forceinline__ unsigned short f2bf(float x) {
  union { float f; unsigned int u; } v; v.f = x;
  unsigned int r = (v.u + 0x7FFFu + ((v.u >> 16) & 1u)) >> 16;
  return (unsigned short)r;
}

__device__ __forceinline__ float bf2f(unsigned short u) {
  union { unsigned int u; float f; } v; v.u = ((unsigned int)u) << 16;
  return v.f;
}

__device__ __forceinline__ us8 cvt8(float4 a, float4 b) {
  us8 o;
  o.u[0] = f2bf(a.x); o.u[1] = f2bf(a.y); o.u[2] = f2bf(a.z); o.u[3] = f2bf(a.w);
  o.u[4] = f2bf(b.x); o.u[5] = f2bf(b.y); o.u[6] = f2bf(b.z); o.u[7] = f2bf(b.w);
  return o;
}

// ---------------- prepass: 7 fp32->bf16 conversions in one launch ----------------
struct CArgs { const float* src[7]; unsigned short* dst[7]; int n8[7]; };

__global__ __launch_bounds__(256)
void cvt_multi(CArgs a)
{
  const int y = blockIdx.y;
  const float* s = a.src[y];
  unsigned short* d = a.dst[y];
  const int n8 = a.n8[y];
  int i = blockIdx.x * blockDim.x + threadIdx.x;
  const int stride = gridDim.x * blockDim.x;
  for (; i < n8; i += stride) {
    float4 va = ((const float4*)s)[(size_t)i * 2];
    float4 vb = ((const float4*)s)[(size_t)i * 2 + 1];
    ((us8*)d)[i] = cvt8(va, vb);
  }
}

// ---------------- prepass: permuted g_eff = bf16(g)|allowed_LSB, 0 if disallowed ----------------
// layout: out[((b*1024+qt*32+kt)*256 + tid)*16 + n*4+rr] = g_eff[q=qt*64+wid*16+colb][kt*64+n*16+hi*4+rr]
__global__ __launch_bounds__(256)
void cvt_gpm(const float* __restrict__ g, const int* __restrict__ m,
             unsigned short* __restrict__ out)
{
  const int idx = blockIdx.x;                 // b*1024 + qt*32 + kt
  const int b = idx >> 10, rest = idx & 1023, qt = rest >> 5, kt = rest & 31;
  const int tid = threadIdx.x;
  const int colb = tid & 15, hi = (tid >> 4) & 3, wid = tid >> 6;
  const int q = qt * 64 + wid * 16 + colb;
  const int k0 = kt * 64 + hi * 4;
  const float* grow = g + ((size_t)b * Sc + q) * Sc + k0;
  const int* mrow = m + ((size_t)b * Sc + q) * Sc + k0;
  unsigned short vals[16];
#pragma unroll
  for (int n = 0; n < 4; ++n) {
    float4 gv = *(const float4*)(grow + n * 16);
    int4 mv = *(const int4*)(mrow + n * 16);
    const int kb = k0 + n * 16;
    const float gg[4] = {gv.x, gv.y, gv.z, gv.w};
    const int mm[4] = {mv.x, mv.y, mv.z, mv.w};
#pragma unroll
    for (int rr = 0; rr < 4; ++rr) {
      const bool allowed = (mm[rr] != 0) || (kb + rr == q);
      vals[n * 4 + rr] = allowed ? (unsigned short)(f2bf(gg[rr]) | 1u) : (unsigned short)0;
    }
  }
  us8* o = (us8*)(out + (((size_t)idx * 256) + tid) * 16);
  o[0] = *(us8*)&vals[0];
  o[1] = *(us8*)&vals[8];
}

// ---------------- 128x128-tile bf16 NT GEMM (m97 structure) ----------------
struct GArgs {
  const unsigned short* A[3];
  const unsigned short* W[3];
  const float* bias[3];
  void* C[3];
  int mode[3];
  float osc[3];      // output scale (mode 0 only)
};

__global__ __launch_bounds__(256)
void gemm128(GArgs ga)
{
  __shared__ unsigned short As[128][64];   // XOR-swizzled rows (128 B, 8 slots)
  __shared__ unsigned short Bs[128][64];

  constexpr int K = 512, N = 512;
  const int z = blockIdx.z;
  const unsigned short* Ap = ga.A[z];
  const unsigned short* Wp = ga.W[z];
  const float* bias = ga.bias[z];
  const int mode = ga.mode[z];
  const float osc = ga.osc[z];

  const int tid = threadIdx.x, lane = tid & 63, w = tid >> 6;
  const int m0 = blockIdx.x * 128, n0 = blockIdx.y * 128;
  const int wm = w >> 1, wn = w & 1;
  const int colb = lane & 15, hi = lane >> 4, rowb = hi * 4;
  const int swz = (colb & 7) << 4;

  f32x4 acc[4][4];
#pragma unroll
  for (int i = 0; i < 4; ++i)
#pragma unroll
    for (int j = 0; j < 4; ++j) acc[i][j] = (f32x4){0.f, 0.f, 0.f, 0.f};

  const int lrow8 = lane >> 3;
  const int cb = ((lane & 7) * 16) ^ (lrow8 << 4);

  for (int k0 = 0; k0 < K; k0 += 64) {
    if (k0) __syncthreads();
#pragma unroll
    for (int i = 0; i < 4; ++i) {
      const int obase = w * 1024 + i * 4096;
      const int row = w * 8 + i * 32 + lrow8;
      const unsigned short* asrc = Ap + (size_t)(m0 + row) * K + k0 + (cb >> 1);
      const unsigned short* bsrc = Wp + (size_t)(n0 + row) * K + k0 + (cb >> 1);
      __builtin_amdgcn_global_load_lds((g_void*)asrc, (lds_void*)((char*)&As[0][0] + obase), 16, 0, 0);
      __builtin_amdgcn_global_load_lds((g_void*)bsrc, (lds_void*)((char*)&Bs[0][0] + obase), 16, 0, 0);
    }
    asm volatile("s_waitcnt vmcnt(0)" ::: "memory");
    __syncthreads();

    char* ab = (char*)&As[0][0];
    char* bb = (char*)&Bs[0][0];
#pragma unroll
    for (int kk = 0; kk < 2; ++kk) {
      bf16x8 af[4], bfr[4];
#pragma unroll
      for (int mf = 0; mf < 4; ++mf) {
        const int ar = wm * 64 + mf * 16 + colb;
        af[mf] = *(const bf16x8*)(ab + ar * 128 + ((kk * 64 + hi * 16) ^ swz));
      }
#pragma unroll
      for (int nf = 0; nf < 4; ++nf) {
        const int br = wn * 64 + nf * 16 + colb;
        bfr[nf] = *(const bf16x8*)(bb + br * 128 + ((kk * 64 + hi * 16) ^ swz));
      }
      __builtin_amdgcn_s_setprio(1);
#pragma unroll
      for (int mf = 0; mf < 4; ++mf)
#pragma unroll
        for (int nf = 0; nf < 4; ++nf)
          acc[mf][nf] = __builtin_amdgcn_mfma_f32_16x16x32_bf16(af[mf], bfr[nf], acc[mf][nf], 0, 0, 0);
      __builtin_amdgcn_s_setprio(0);
    }
  }

#pragma unroll
  for (int nf = 0; nf < 4; ++nf) {
    const int gn = n0 + wn * 64 + nf * 16 + colb;
    const float bv = bias[gn];
    if (mode == 1) {
      unsigned short* Cp = (unsigned short*)ga.C[z];
#pragma unroll
      for (int mf = 0; mf < 4; ++mf) {
        const int gm = m0 + wm * 64 + mf * 16 + rowb;
        const int bb_ = gm >> 11, ss = gm & (Sc - 1);
        us4 vv;
#pragma unroll
        for (int rr = 0; rr < 4; ++rr) vv.u[rr] = f2bf(acc[mf][nf][rr] + bv);
        *(us4*)(Cp + ((size_t)bb_ * N + gn) * Sc + ss) = vv;
      }
    } else if (mode == 0) {
      unsigned short* Cp = (unsigned short*)ga.C[z];
#pragma unroll
      for (int mf = 0; mf < 4; ++mf)
#pragma unroll
        for (int rr = 0; rr < 4; ++rr) {
          const int gm = m0 + wm * 64 + mf * 16 + rowb + rr;
          Cp[(size_t)gm * N + gn] = f2bf((acc[mf][nf][rr] + bv) * osc);
        }
    } else {
      float* Cp = (float*)ga.C[z];
#pragma unroll
      for (int mf = 0; mf < 4; ++mf)
#pragma unroll
        for (int rr = 0; rr < 4; ++rr) {
          const int gm = m0 + wm * 64 + mf * 16 + rowb + rr;
          Cp[(size_t)gm * N + gn] = acc[mf][nf][rr] + bv;
        }
    }
  }
}

// ---------------- split-K flash attention (S^T, exp2, defer-max, LDS-staged K/V, permuted g) ----------------
// grid (B*H, S/64, SPLIT). Partials: Pacc[blk][d=64][q=64] (O^T), Pml[blk][2][64] (m log2-domain).
__global__ __launch_bounds__(256, 4)
void attn_split(const unsigned short* __restrict__ Qb,
                const unsigned short* __restrict__ Kb,
                const unsigned short* __restrict__ Vt,
                const unsigned short* __restrict__ Gp,
                float* __restrict__ Pacc,
                float* __restrict__ Pml)
{
  __shared__ unsigned short Ks[2][64][64];   // [k][dk], XOR-swizzled rows
  __shared__ unsigned short Vs[2][64][64];   // [dk][k], XOR-swizzled rows
  __shared__ unsigned short Ps[4][16][64];   // per-wave P [q][k], XOR-swizzled rows

  const int tid = threadIdx.x, lane = tid & 63, wid = tid >> 6;
  const int bh = blockIdx.x, b = bh >> 3, h = bh & 7;
  const int qt = blockIdx.y, q0 = qt * 64;
  const int sp = blockIdx.z;
  const int kt0 = sp * KT_PER;

  const int colb = lane & 15;
  const int hi = lane >> 4;
  const int rowb = hi * 4;
  const int c3s = (colb & 7) << 4;

  // Q fragment (pre-scaled by CSC at projection): lane holds Q[q=wid*16+colb][d=hi*8+j]
  bf16x8 qf[2];
  {
    const unsigned short* qp = Qb + ((size_t)(b * Sc + q0 + wid * 16 + colb) * Dc + h * DKc + hi * 8);
    qf[0] = *(const bf16x8*)qp;
    qf[1] = *(const bf16x8*)(qp + 32);
  }

  f32x4 acc[4] = {{0,0,0,0},{0,0,0,0},{0,0,0,0},{0,0,0,0}};   // acc[n][rr] = O^T[n*16+rowb+rr][q]
  float mrun = -1e30f, lrun = 0.f;

  auto stageKV = [&](int bufI, int kt) {
    const int k0 = kt * 64;
#pragma unroll
    for (int i = 0; i < 2; ++i) {
      const int obase = wid * 1024 + i * 4096;
      const int row = (obase >> 7) + (lane >> 3);
      const int cb = ((lane & 7) * 16) ^ ((row & 7) << 4);
      const unsigned short* ksrc = Kb + (size_t)(b * Sc + k0 + row) * Dc + h * DKc + (cb >> 1);
      const unsigned short* vsrc = Vt + ((size_t)b * Dc + h * DKc + row) * Sc + k0 + (cb >> 1);
      __builtin_amdgcn_global_load_lds((g_void*)ksrc, (lds_void*)((char*)&Ks[bufI][0][0] + obase), 16, 0, 0);
      __builtin_amdgcn_global_load_lds((g_void*)vsrc, (lds_void*)((char*)&Vs[bufI][0][0] + obase), 16, 0, 0);
    }
  };

  // pre-permuted g (coalesced 32 B/lane per tile); allowed-bit lives in bf16 LSB
  const unsigned short* gtile = Gp + (((size_t)(b * 1024 + qt * 32)) * 256 + tid) * 16;
  us8 gcur0, gcur1;
  auto loadG = [&](int kt, us8& g0, us8& g1) {
    const us8* p = (const us8*)(gtile + (size_t)kt * 4096);
    g0 = p[0]; g1 = p[1];
  };

  stageKV(0, kt0);
  loadG(kt0, gcur0, gcur1);
  asm volatile("s_waitcnt vmcnt(0)" ::: "memory");
  __syncthreads();

  int buf = 0;
  char* psbase = (char*)&Ps[wid][0][0];

  for (int j = 0; j < KT_PER; ++j) {
    const int kt = kt0 + j;
    us8 gn0, gn1;
    if (j + 1 < KT_PER) {
      stageKV(buf ^ 1, kt + 1);
      loadG(kt + 1, gn0, gn1);
    }

    // S^T = K Q^T : sf[n][rr] = S[q=colb][k = n*16 + hi*4 + rr]  (CSC pre-scaled via Q)
    f32x4 sf[4] = {{0,0,0,0},{0,0,0,0},{0,0,0,0},{0,0,0,0}};
    char* ksb = (char*)&Ks[buf][0][0];
    __builtin_amdgcn_s_setprio(1);
#pragma unroll
    for (int kk = 0; kk < 2; ++kk) {
#pragma unroll
      for (int n = 0; n < 4; ++n) {
        const int krow = n * 16 + colb;
        bf16x8 kf = *(const bf16x8*)(ksb + krow * 128 + ((kk * 64 + hi * 16) ^ ((krow & 7) << 4)));
        sf[n] = __builtin_amdgcn_mfma_f32_16x16x32_bf16(kf, qf[kk], sf[n], 0, 0, 0);
      }
    }
    __builtin_amdgcn_s_setprio(0);

    // unmasked row max (common scale cancels; gating via g LSB)
    float tm = sf[0][0];
#pragma unroll
    for (int n = 0; n < 4; ++n)
#pragma unroll
      for (int rr = 0; rr < 4; ++rr) tm = fmaxf(tm, sf[n][rr]);
    tm = fmaxf(tm, __shfl_xor(tm, 16));
    tm = fmaxf(tm, __shfl_xor(tm, 32));

    // defer-max: rescale only when some row grows by >8 (log2); P bounded by 2^8
    if (__any(tm > mrun + 8.f)) {
      const float mnew = fmaxf(mrun, tm);
      const float alpha = __builtin_amdgcn_exp2f(mrun - mnew);
      mrun = mnew;
#pragma unroll
      for (int n = 0; n < 4; ++n)
#pragma unroll
        for (int rr = 0; rr < 4; ++rr) acc[n][rr] *= alpha;
      lrun *= alpha;
    }

    // p = exp2(s-m); numerator uses g_eff (0 at disallowed); denominator gated by LSB
    float rsum = 0.f;
    unsigned int pw[8];
#pragma unroll
    for (int n = 0; n < 4; ++n) {
#pragma unroll
      for (int s2 = 0; s2 < 2; ++s2) {
        const int jv = n * 4 + s2 * 2;
        const unsigned short u0 = (jv < 8) ? gcur0.u[jv] : gcur1.u[jv - 8];
        const unsigned short u1 = (jv + 1 < 8) ? gcur0.u[jv + 1] : gcur1.u[jv + 1 - 8];
        const float p0 = __builtin_amdgcn_exp2f(sf[n][s2 * 2]     - mrun);
        const float p1 = __builtin_amdgcn_exp2f(sf[n][s2 * 2 + 1] - mrun);
        rsum = fmaf(p0, (float)(u0 & 1u), rsum);
        rsum = fmaf(p1, (float)(u1 & 1u), rsum);
        const float q0v = p0 * bf2f(u0), q1v = p1 * bf2f(u1);
        asm("v_cvt_pk_bf16_f32 %0, %1, %2" : "=v"(pw[n * 2 + s2]) : "v"(q0v), "v"(q1v));
      }
    }
    rsum += __shfl_xor(rsum, 16);
    rsum += __shfl_xor(rsum, 32);
    lrun += rsum;

    // store P [q=colb][k] as 4x ds_write_b64
#pragma unroll
    for (int n = 0; n < 4; ++n) {
      const unsigned long long w64 = ((unsigned long long)pw[n * 2 + 1] << 32) | pw[n * 2];
      *(unsigned long long*)(psbase + colb * 128 + ((n * 32 + hi * 8) ^ c3s)) = w64;
    }

    // acc += V^T P^T  (O^T layout; Ps wave-private)
    char* vsb = (char*)&Vs[buf][0][0];
    __builtin_amdgcn_s_setprio(1);
#pragma unroll
    for (int kk = 0; kk < 2; ++kk) {
      bf16x8 pf = *(const bf16x8*)(psbase + colb * 128 + ((kk * 64 + hi * 16) ^ c3s));
#pragma unroll
      for (int n = 0; n < 4; ++n) {
        const int vrow = n * 16 + colb;
        bf16x8 vf = *(const bf16x8*)(vsb + vrow * 128 + ((kk * 64 + hi * 16) ^ ((vrow & 7) << 4)));
        acc[n] = __builtin_amdgcn_mfma_f32_16x16x32_bf16(vf, pf, acc[n], 0, 0, 0);
      }
    }
    __builtin_amdgcn_s_setprio(0);

    asm volatile("s_waitcnt vmcnt(0)" ::: "memory");
    __syncthreads();
    buf ^= 1;
    if (j + 1 < KT_PER) { gcur0 = gn0; gcur1 = gn1; }
  }

  // write partials (O^T layout: [d][q])
  const size_t blin = ((size_t)bh * 32 + qt) * SPLIT + sp;
  float* pa = Pacc + blin * 4096;
#pragma unroll
  for (int n = 0; n < 4; ++n)
#pragma unroll
    for (int rr = 0; rr < 4; ++rr)
      pa[(size_t)(n * 16 + rowb + rr) * 64 + wid * 16 + colb] = acc[n][rr];
  if (hi == 0) {
    float* pm = Pml + blin * 128;
    pm[wid * 16 + colb] = mrun;
    pm[64 + wid * 16 + colb] = lrun;
  }
}

// ---------------- recombine split partials -> bf16 X (m in log2 domain) ----------------
__global__ __launch_bounds__(256)
void attn_reduce(const float* __restrict__ Pacc, const float* __restrict__ Pml,
                 unsigned short* __restrict__ Xb)
{
  const int gidx = blockIdx.x;      // bh*32 + qt
  const int bh = gidx >> 5, qt = gidx & 31;
  const int b = bh >> 3, h = bh & 7;
  const int tid = threadIdx.x;
  const int qi = tid & 63;
  const int d0 = (tid >> 6) * 16;
  const size_t pb = (size_t)gidx * SPLIT;

  float m[SPLIT], l[SPLIT];
  float mstar = -3.0e38f;
#pragma unroll
  for (int s = 0; s < SPLIT; ++s) {
    m[s] = Pml[(pb + s) * 128 + qi];
    l[s] = Pml[(pb + s) * 128 + 64 + qi];
    mstar = fmaxf(mstar, m[s]);
  }
  float w[SPLIT], denom = 0.f;
#pragma unroll
  for (int s = 0; s < SPLIT; ++s) { w[s] = __builtin_amdgcn_exp2f(m[s] - mstar); denom += w[s] * l[s]; }
  const float inv = 1.0f / denom;

  unsigned short vals[16];
#pragma unroll
  for (int j = 0; j < 16; ++j) {
    float a = 0.f;
#pragma unroll
    for (int s = 0; s < SPLIT; ++s)
      a += w[s] * Pacc[(pb + s) * 4096 + (size_t)(d0 + j) * 64 + qi];
    vals[j] = f2bf(a * inv);
  }
  unsigned short* xp = Xb + ((size_t)(b * Sc) + qt * 64 + qi) * Dc + h * DKc + d0;
  *(us8*)xp = *(us8*)&vals[0];
  *(us8*)(xp + 8) = *(us8*)&vals[8];
}

extern "C" void kernel_launch(void* const* d_in, const int* in_sizes, int n_in,
                              void* d_out, int out_size, void* d_ws, size_t ws_size,
                              hipStream_t stream)
{
  const float* query = (const float*)d_in[0];
  const float* key_  = (const float*)d_in[1];
  const float* value = (const float*)d_in[2];
  const float* gprob = (const float*)d_in[3];
  const int*   mask  = (const int*)d_in[4];
  const float* Wq = (const float*)d_in[5];
  const float* bq = (const float*)d_in[6];
  const float* Wk = (const float*)d_in[7];
  const float* bk = (const float*)d_in[8];
  const float* Wv = (const float*)d_in[9];
  const float* bv = (const float*)d_in[10];
  const float* Wo = (const float*)d_in[11];
  const float* bo = (const float*)d_in[12];
  float* out = (float*)d_out;

  const size_t elems = (size_t)Bc * Sc * Dc;     // 2 Mi
  const size_t gelems = (size_t)Bc * Sc * Sc;    // 8 Mi
  const size_t welems = (size_t)Dc * Dc;         // 256 Ki

  char* base = (char*)d_ws;
  unsigned short* Qb = (unsigned short*)(base);                    // 4 MB
  unsigned short* Kb = Qb + elems;                                 // 4 MB
  unsigned short* Vt = Kb + elems;                                 // 4 MB
  unsigned short* Xb = Vt + elems;                                 // 4 MB
  unsigned short* Gp = Xb + elems;                                 // 16.8 MB (permuted masked bf16 g, LSB=allowed)
  char* shared_region = (char*)(Gp + gelems);
  // shared region: first bf16 copies of q/k/v inputs, later split partials
  unsigned short* Ain = (unsigned short*)shared_region;            // 4 MB
  unsigned short* Bin = Ain + elems;                               // 4 MB
  unsigned short* Cin = Bin + elems;                               // 4 MB
  float* Pacc = (float*)shared_region;                             // 16.8 MB
  float* Pml  = Pacc + (size_t)(Bc * Hc) * 32 * SPLIT * 4096;      // 0.5 MB
  // weights (bf16) past the shared region's max extent
  unsigned short* Wqb = (unsigned short*)(shared_region + (18u << 20));
  unsigned short* Wkb = Wqb + welems;
  unsigned short* Wvb = Wkb + welems;
  unsigned short* Wob = Wvb + welems;

  // prepasses
  CArgs ca;
  ca.src[0] = query; ca.dst[0] = Ain; ca.n8[0] = (int)(elems / 8);
  ca.src[1] = key_;  ca.dst[1] = Bin; ca.n8[1] = (int)(elems / 8);
  ca.src[2] = value; ca.dst[2] = Cin; ca.n8[2] = (int)(elems / 8);
  ca.src[3] = Wq;    ca.dst[3] = Wqb; ca.n8[3] = (int)(welems / 8);
  ca.src[4] = Wk;    ca.dst[4] = Wkb; ca.n8[4] = (int)(welems / 8);
  ca.src[5] = Wv;    ca.dst[5] = Wvb; ca.n8[5] = (int)(welems / 8);
  ca.src[6] = Wo;    ca.dst[6] = Wob; ca.n8[6] = (int)(welems / 8);
  hipLaunchKernelGGL(cvt_multi, dim3(128, 7), dim3(256), 0, stream, ca);
  hipLaunchKernelGGL(cvt_gpm, dim3(2048), dim3(256), 0, stream, gprob, mask, Gp);

  // fused Q/K/V projections (Q output pre-scaled by CSC)
  GArgs gq;
  gq.A[0] = Ain; gq.W[0] = Wqb; gq.bias[0] = bq; gq.C[0] = (void*)Qb; gq.mode[0] = 0; gq.osc[0] = CSC;
  gq.A[1] = Bin; gq.W[1] = Wkb; gq.bias[1] = bk; gq.C[1] = (void*)Kb; gq.mode[1] = 0; gq.osc[1] = 1.0f;
  gq.A[2] = Cin; gq.W[2] = Wvb; gq.bias[2] = bv; gq.C[2] = (void*)Vt; gq.mode[2] = 1; gq.osc[2] = 1.0f;
  hipLaunchKernelGGL(gemm128, dim3(32, 4, 3), dim3(256), 0, stream, gq);

  dim3 ga(Bc * Hc, Sc / 64, SPLIT);
  hipLaunchKernelGGL(attn_split, ga, dim3(256), 0, stream, Qb, Kb, Vt, Gp, Pacc, Pml);
  hipLaunchKernelGGL(attn_reduce, dim3(Bc * Hc * 32), dim3(256), 0, stream, Pacc, Pml, Xb);

  // output projection
  GArgs go;
  go.A[0] = Xb; go.W[0] = Wob; go.bias[0] = bo; go.C[0] = (void*)out; go.mode[0] = 2; go.osc[0] = 1.0f;
  go.A[1] = Xb; go.W[1] = Wob; go.bias[1] = bo; go.C[1] = (void*)out; go.mode[1] = 2; go.osc[1] = 1.0f;
  go.A[2] = Xb; go.W[2] = Wob; go.bias[2] = bo; go.C[2] = (void*)out; go.mode[2] = 2; go.osc[2] = 1.0f;
  hipLaunchKernelGGL(gemm128, dim3(32, 4, 1), dim3(256), 0, stream, go);
}

// Round 10
// 101.275 us; speedup vs baseline: 2.0558x; 1.0160x over previous
//
#include <hip/hip_runtime.h>
#include <hip/hip_bf16.h>
#include <cstdint>
#include <cstddef>

typedef __attribute__((ext_vector_type(8))) short bf16x8;
typedef __attribute__((ext_vector_type(4))) float f32x4;
typedef __attribute__((address_space(3))) void lds_void;
typedef const __attribute__((address_space(1))) void g_void;

constexpr int Bc = 2, Sc = 2048, Dc = 512, Hc = 8, DKc = 64;
constexpr int SPLIT = 2;
constexpr int NKT = Sc / 64;           // 32 k-tiles total
constexpr int KT_PER = NKT / SPLIT;    // 16 per block
constexpr float CSC = 0.18033688011112042f;  // 0.125 * log2(e), folded into Q projection

struct alignas(16) us8 { unsigned short u[8]; };
struct alignas(8) us4 { unsigned short u[4]; };

__device__ __forceinline__ unsigned short f2bf(float x) {
  union { float f; unsigned int u; } v; v.f = x;
  unsigned int r = (v.u + 0x7FFFu + ((v.u >> 16) & 1u)) >> 16;
  return (unsigned short)r;
}

__device__ __forceinline__ float bf2f(unsigned short u) {
  union { unsigned int u; float f; } v; v.u = ((unsigned int)u) << 16;
  return v.f;
}

__device__ __forceinline__ us8 cvt8(float4 a, float4 b) {
  us8 o;
  o.u[0] = f2bf(a.x); o.u[1] = f2bf(a.y); o.u[2] = f2bf(a.z); o.u[3] = f2bf(a.w);
  o.u[4] = f2bf(b.x); o.u[5] = f2bf(b.y); o.u[6] = f2bf(b.z); o.u[7] = f2bf(b.w);
  return o;
}

// ---------------- prepass: permuted g_eff (+LSB gate) AND weight fp32->bf16, one launch ----------------
// blocks 0..2047: g_eff tiles; blocks 2048..2079: weight conversion.
struct PArgs {
  const float* g; const int* m; unsigned short* gp;
  const float* wsrc[4]; unsigned short* wdst[4];
};

__global__ __launch_bounds__(256)
void prepass(PArgs pa)
{
  const int bx = blockIdx.x;
  const int tid = threadIdx.x;
  if (bx < 2048) {
    // out[((b*1024+qt*32+kt)*256 + tid)*16 + n*4+rr] = g_eff[q][kt*64+n*16+hi*4+rr], LSB=allowed
    const int idx = bx;
    const int b = idx >> 10, rest = idx & 1023, qt = rest >> 5, kt = rest & 31;
    const int colb = tid & 15, hi = (tid >> 4) & 3, wid = tid >> 6;
    const int q = qt * 64 + wid * 16 + colb;
    const int k0 = kt * 64 + hi * 4;
    const float* grow = pa.g + ((size_t)b * Sc + q) * Sc + k0;
    const int* mrow = pa.m + ((size_t)b * Sc + q) * Sc + k0;
    unsigned short vals[16];
#pragma unroll
    for (int n = 0; n < 4; ++n) {
      float4 gv = *(const float4*)(grow + n * 16);
      int4 mv = *(const int4*)(mrow + n * 16);
      const int kb = k0 + n * 16;
      const float gg[4] = {gv.x, gv.y, gv.z, gv.w};
      const int mm[4] = {mv.x, mv.y, mv.z, mv.w};
#pragma unroll
      for (int rr = 0; rr < 4; ++rr) {
        const bool allowed = (mm[rr] != 0) || (kb + rr == q);
        vals[n * 4 + rr] = allowed ? (unsigned short)(f2bf(gg[rr]) | 1u) : (unsigned short)0;
      }
    }
    us8* o = (us8*)(pa.gp + (((size_t)idx * 256) + tid) * 16);
    o[0] = *(us8*)&vals[0];
    o[1] = *(us8*)&vals[8];
  } else {
    const int r = bx - 2048;            // 0..31
    const int wi = r >> 3, sub = r & 7; // weight idx, sub-block
    const float* s = pa.wsrc[wi];
    unsigned short* d = pa.wdst[wi];
#pragma unroll
    for (int t = 0; t < 16; ++t) {
      const int i = sub * 4096 + t * 256 + tid;   // 32768 us8-groups per 512x512 weight
      float4 a = ((const float4*)s)[(size_t)i * 2];
      float4 b = ((const float4*)s)[(size_t)i * 2 + 1];
      ((us8*)d)[i] = cvt8(a, b);
    }
  }
}

// ---------------- 128x64-tile bf16 NT GEMM ----------------
// C = A * W^T + bias.  A fp32 (reg-staged cvt) or bf16 (global_load_lds); W bf16.
// mode 0: bf16 [M,N] (scaled by osc); 1: bf16 per-batch transposed [b][n][s]; 2: fp32 [M,N].
struct GArgs {
  const void* A[3];
  const unsigned short* W[3];
  const float* bias[3];
  void* C[3];
  int mode[3];
  float osc[3];
};

template<int A_FP32>
__global__ __launch_bounds__(256)
void gemm_bn64(GArgs ga)
{
  __shared__ unsigned short As[128][64];   // 16 KB, XOR-swizzled rows
  __shared__ unsigned short Bs[64][64];    // 8 KB

  constexpr int K = 512, N = 512;
  const int z = blockIdx.z;
  const unsigned short* Wp = ga.W[z];
  const float* bias = ga.bias[z];
  const int mode = ga.mode[z];
  const float osc = ga.osc[z];

  const int tid = threadIdx.x, lane = tid & 63, w = tid >> 6;
  const int m0 = blockIdx.x * 128, n0 = blockIdx.y * 64;
  const int wm = w >> 1, wn = w & 1;                 // wave owns 64m x 32n
  const int colb = lane & 15, hi = lane >> 4, rowb = hi * 4;
  const int swz = (colb & 7) << 4;

  f32x4 acc[4][2];
#pragma unroll
  for (int i = 0; i < 4; ++i)
#pragma unroll
    for (int j = 0; j < 2; ++j) acc[i][j] = (f32x4){0.f, 0.f, 0.f, 0.f};

  const int lrow8 = lane >> 3;
  const int cb = ((lane & 7) * 16) ^ (lrow8 << 4);   // pre-swizzled src col (bf16 bytes)

  for (int k0 = 0; k0 < K; k0 += 64) {
    if (k0) __syncthreads();
    // B staging: 2 async units/wave
#pragma unroll
    for (int i = 0; i < 2; ++i) {
      const int u = w + i * 4;
      const int row = u * 8 + lrow8;
      const unsigned short* bsrc = Wp + (size_t)(n0 + row) * K + k0 + (cb >> 1);
      __builtin_amdgcn_global_load_lds((g_void*)bsrc, (lds_void*)((char*)&Bs[0][0] + u * 1024), 16, 0, 0);
    }
    // A staging: 4 units/wave
    if (A_FP32) {
      const float* Af = (const float*)ga.A[z];
#pragma unroll
      for (int i = 0; i < 4; ++i) {
        const int u = w * 4 + i;
        const int row = u * 8 + lrow8;
        const float* src = Af + (size_t)(m0 + row) * K + k0 + (cb >> 1);
        float4 v0 = *(const float4*)src, v1 = *(const float4*)(src + 4);
        // linear dest + pre-swizzled source == global_load_lds net layout
        *(us8*)((char*)&As[0][0] + u * 1024 + lane * 16) = cvt8(v0, v1);
      }
    } else {
      const unsigned short* Ab = (const unsigned short*)ga.A[z];
#pragma unroll
      for (int i = 0; i < 4; ++i) {
        const int u = w * 4 + i;
        const int row = u * 8 + lrow8;
        const unsigned short* asrc = Ab + (size_t)(m0 + row) * K + k0 + (cb >> 1);
        __builtin_amdgcn_global_load_lds((g_void*)asrc, (lds_void*)((char*)&As[0][0] + u * 1024), 16, 0, 0);
      }
    }
    asm volatile("s_waitcnt vmcnt(0)" ::: "memory");
    __syncthreads();

    char* ab = (char*)&As[0][0];
    char* bb = (char*)&Bs[0][0];
#pragma unroll
    for (int kk = 0; kk < 2; ++kk) {
      bf16x8 af[4], bfr[2];
#pragma unroll
      for (int mf = 0; mf < 4; ++mf) {
        const int ar = wm * 64 + mf * 16 + colb;
        af[mf] = *(const bf16x8*)(ab + ar * 128 + ((kk * 64 + hi * 16) ^ swz));
      }
#pragma unroll
      for (int nf = 0; nf < 2; ++nf) {
        const int br = wn * 32 + nf * 16 + colb;
        bfr[nf] = *(const bf16x8*)(bb + br * 128 + ((kk * 64 + hi * 16) ^ swz));
      }
      __builtin_amdgcn_s_setprio(1);
#pragma unroll
      for (int mf = 0; mf < 4; ++mf)
#pragma unroll
        for (int nf = 0; nf < 2; ++nf)
          acc[mf][nf] = __builtin_amdgcn_mfma_f32_16x16x32_bf16(af[mf], bfr[nf], acc[mf][nf], 0, 0, 0);
      __builtin_amdgcn_s_setprio(0);
    }
  }

#pragma unroll
  for (int nf = 0; nf < 2; ++nf) {
    const int gn = n0 + wn * 32 + nf * 16 + colb;
    const float bv = bias[gn];
    if (mode == 1) {
      unsigned short* Cp = (unsigned short*)ga.C[z];
#pragma unroll
      for (int mf = 0; mf < 4; ++mf) {
        const int gm = m0 + wm * 64 + mf * 16 + rowb;
        const int bb_ = gm >> 11, ss = gm & (Sc - 1);
        us4 vv;
#pragma unroll
        for (int rr = 0; rr < 4; ++rr) vv.u[rr] = f2bf(acc[mf][nf][rr] + bv);
        *(us4*)(Cp + ((size_t)bb_ * N + gn) * Sc + ss) = vv;
      }
    } else if (mode == 0) {
      unsigned short* Cp = (unsigned short*)ga.C[z];
#pragma unroll
      for (int mf = 0; mf < 4; ++mf)
#pragma unroll
        for (int rr = 0; rr < 4; ++rr) {
          const int gm = m0 + wm * 64 + mf * 16 + rowb + rr;
          Cp[(size_t)gm * N + gn] = f2bf((acc[mf][nf][rr] + bv) * osc);
        }
    } else {
      float* Cp = (float*)ga.C[z];
#pragma unroll
      for (int mf = 0; mf < 4; ++mf)
#pragma unroll
        for (int rr = 0; rr < 4; ++rr) {
          const int gm = m0 + wm * 64 + mf * 16 + rowb + rr;
          Cp[(size_t)gm * N + gn] = acc[mf][nf][rr] + bv;
        }
    }
  }
}

// ---------------- split-K flash attention (S^T, exp2, defer-max, LDS-staged K/V, permuted g) ----------------
// grid (B*H, S/64, SPLIT). Partials: Pacc[blk][d=64][q=64] (O^T), Pml[blk][2][64] (m log2-domain).
__global__ __launch_bounds__(256, 4)
void attn_split(const unsigned short* __restrict__ Qb,
                const unsigned short* __restrict__ Kb,
                const unsigned short* __restrict__ Vt,
                const unsigned short* __restrict__ Gp,
                float* __restrict__ Pacc,
                float* __restrict__ Pml)
{
  __shared__ unsigned short Ks[2][64][64];   // [k][dk], XOR-swizzled rows
  __shared__ unsigned short Vs[2][64][64];   // [dk][k], XOR-swizzled rows
  __shared__ unsigned short Ps[4][16][64];   // per-wave P [q][k], XOR-swizzled rows

  const int tid = threadIdx.x, lane = tid & 63, wid = tid >> 6;
  const int bh = blockIdx.x, b = bh >> 3, h = bh & 7;
  const int qt = blockIdx.y, q0 = qt * 64;
  const int sp = blockIdx.z;
  const int kt0 = sp * KT_PER;

  const int colb = lane & 15;
  const int hi = lane >> 4;
  const int rowb = hi * 4;
  const int c3s = (colb & 7) << 4;

  // Q fragment (pre-scaled by CSC at projection): lane holds Q[q=wid*16+colb][d=hi*8+j]
  bf16x8 qf[2];
  {
    const unsigned short* qp = Qb + ((size_t)(b * Sc + q0 + wid * 16 + colb) * Dc + h * DKc + hi * 8);
    qf[0] = *(const bf16x8*)qp;
    qf[1] = *(const bf16x8*)(qp + 32);
  }

  f32x4 acc[4] = {{0,0,0,0},{0,0,0,0},{0,0,0,0},{0,0,0,0}};   // acc[n][rr] = O^T[n*16+rowb+rr][q]
  float mrun = -1e30f, lrun = 0.f;

  auto stageKV = [&](int bufI, int kt) {
    const int k0 = kt * 64;
#pragma unroll
    for (int i = 0; i < 2; ++i) {
      const int obase = wid * 1024 + i * 4096;
      const int row = (obase >> 7) + (lane >> 3);
      const int cb = ((lane & 7) * 16) ^ ((row & 7) << 4);
      const unsigned short* ksrc = Kb + (size_t)(b * Sc + k0 + row) * Dc + h * DKc + (cb >> 1);
      const unsigned short* vsrc = Vt + ((size_t)b * Dc + h * DKc + row) * Sc + k0 + (cb >> 1);
      __builtin_amdgcn_global_load_lds((g_void*)ksrc, (lds_void*)((char*)&Ks[bufI][0][0] + obase), 16, 0, 0);
      __builtin_amdgcn_global_load_lds((g_void*)vsrc, (lds_void*)((char*)&Vs[bufI][0][0] + obase), 16, 0, 0);
    }
  };

  // pre-permuted g (coalesced 32 B/lane per tile); allowed-bit lives in bf16 LSB
  const unsigned short* gtile = Gp + (((size_t)(b * 1024 + qt * 32)) * 256 + tid) * 16;
  us8 gcur0, gcur1;
  auto loadG = [&](int kt, us8& g0, us8& g1) {
    const us8* p = (const us8*)(gtile + (size_t)kt * 4096);
    g0 = p[0]; g1 = p[1];
  };

  stageKV(0, kt0);
  loadG(kt0, gcur0, gcur1);
  asm volatile("s_waitcnt vmcnt(0)" ::: "memory");
  __syncthreads();

  int buf = 0;
  char* psbase = (char*)&Ps[wid][0][0];

  for (int j = 0; j < KT_PER; ++j) {
    const int kt = kt0 + j;
    us8 gn0, gn1;
    if (j + 1 < KT_PER) {
      stageKV(buf ^ 1, kt + 1);
      loadG(kt + 1, gn0, gn1);
    }

    // S^T = K Q^T : sf[n][rr] = S[q=colb][k = n*16 + hi*4 + rr]  (CSC pre-scaled via Q)
    f32x4 sf[4] = {{0,0,0,0},{0,0,0,0},{0,0,0,0},{0,0,0,0}};
    char* ksb = (char*)&Ks[buf][0][0];
    __builtin_amdgcn_s_setprio(1);
#pragma unroll
    for (int kk = 0; kk < 2; ++kk) {
#pragma unroll
      for (int n = 0; n < 4; ++n) {
        const int krow = n * 16 + colb;
        bf16x8 kf = *(const bf16x8*)(ksb + krow * 128 + ((kk * 64 + hi * 16) ^ ((krow & 7) << 4)));
        sf[n] = __builtin_amdgcn_mfma_f32_16x16x32_bf16(kf, qf[kk], sf[n], 0, 0, 0);
      }
    }
    __builtin_amdgcn_s_setprio(0);

    // unmasked row max (common scale cancels; gating via g LSB)
    float tm = sf[0][0];
#pragma unroll
    for (int n = 0; n < 4; ++n)
#pragma unroll
      for (int rr = 0; rr < 4; ++rr) tm = fmaxf(tm, sf[n][rr]);
    tm = fmaxf(tm, __shfl_xor(tm, 16));
    tm = fmaxf(tm, __shfl_xor(tm, 32));

    // defer-max: rescale only when some row grows by >8 (log2); P bounded by 2^8
    if (__any(tm > mrun + 8.f)) {
      const float mnew = fmaxf(mrun, tm);
      const float alpha = __builtin_amdgcn_exp2f(mrun - mnew);
      mrun = mnew;
#pragma unroll
      for (int n = 0; n < 4; ++n)
#pragma unroll
        for (int rr = 0; rr < 4; ++rr) acc[n][rr] *= alpha;
      lrun *= alpha;
    }

    // p = exp2(s-m); numerator uses g_eff (0 at disallowed); denominator gated by LSB
    float rsum = 0.f;
    unsigned int pw[8];
#pragma unroll
    for (int n = 0; n < 4; ++n) {
#pragma unroll
      for (int s2 = 0; s2 < 2; ++s2) {
        const int jv = n * 4 + s2 * 2;
        const unsigned short u0 = (jv < 8) ? gcur0.u[jv] : gcur1.u[jv - 8];
        const unsigned short u1 = (jv + 1 < 8) ? gcur0.u[jv + 1] : gcur1.u[jv + 1 - 8];
        const float p0 = __builtin_amdgcn_exp2f(sf[n][s2 * 2]     - mrun);
        const float p1 = __builtin_amdgcn_exp2f(sf[n][s2 * 2 + 1] - mrun);
        rsum = fmaf(p0, (float)(u0 & 1u), rsum);
        rsum = fmaf(p1, (float)(u1 & 1u), rsum);
        const float q0v = p0 * bf2f(u0), q1v = p1 * bf2f(u1);
        asm("v_cvt_pk_bf16_f32 %0, %1, %2" : "=v"(pw[n * 2 + s2]) : "v"(q0v), "v"(q1v));
      }
    }
    rsum += __shfl_xor(rsum, 16);
    rsum += __shfl_xor(rsum, 32);
    lrun += rsum;

    // store P [q=colb][k] as 4x ds_write_b64
#pragma unroll
    for (int n = 0; n < 4; ++n) {
      const unsigned long long w64 = ((unsigned long long)pw[n * 2 + 1] << 32) | pw[n * 2];
      *(unsigned long long*)(psbase + colb * 128 + ((n * 32 + hi * 8) ^ c3s)) = w64;
    }

    // acc += V^T P^T  (O^T layout; Ps wave-private)
    char* vsb = (char*)&Vs[buf][0][0];
    __builtin_amdgcn_s_setprio(1);
#pragma unroll
    for (int kk = 0; kk < 2; ++kk) {
      bf16x8 pf = *(const bf16x8*)(psbase + colb * 128 + ((kk * 64 + hi * 16) ^ c3s));
#pragma unroll
      for (int n = 0; n < 4; ++n) {
        const int vrow = n * 16 + colb;
        bf16x8 vf = *(const bf16x8*)(vsb + vrow * 128 + ((kk * 64 + hi * 16) ^ ((vrow & 7) << 4)));
        acc[n] = __builtin_amdgcn_mfma_f32_16x16x32_bf16(vf, pf, acc[n], 0, 0, 0);
      }
    }
    __builtin_amdgcn_s_setprio(0);

    asm volatile("s_waitcnt vmcnt(0)" ::: "memory");
    __syncthreads();
    buf ^= 1;
    if (j + 1 < KT_PER) { gcur0 = gn0; gcur1 = gn1; }
  }

  // write partials (O^T layout: [d][q])
  const size_t blin = ((size_t)bh * 32 + qt) * SPLIT + sp;
  float* pa = Pacc + blin * 4096;
#pragma unroll
  for (int n = 0; n < 4; ++n)
#pragma unroll
    for (int rr = 0; rr < 4; ++rr)
      pa[(size_t)(n * 16 + rowb + rr) * 64 + wid * 16 + colb] = acc[n][rr];
  if (hi == 0) {
    float* pm = Pml + blin * 128;
    pm[wid * 16 + colb] = mrun;
    pm[64 + wid * 16 + colb] = lrun;
  }
}

// ---------------- recombine split partials -> bf16 X (m in log2 domain) ----------------
__global__ __launch_bounds__(256)
void attn_reduce(const float* __restrict__ Pacc, const float* __restrict__ Pml,
                 unsigned short* __restrict__ Xb)
{
  const int gidx = blockIdx.x;      // bh*32 + qt
  const int bh = gidx >> 5, qt = gidx & 31;
  const int b = bh >> 3, h = bh & 7;
  const int tid = threadIdx.x;
  const int qi = tid & 63;
  const int d0 = (tid >> 6) * 16;
  const size_t pb = (size_t)gidx * SPLIT;

  float m[SPLIT], l[SPLIT];
  float mstar = -3.0e38f;
#pragma unroll
  for (int s = 0; s < SPLIT; ++s) {
    m[s] = Pml[(pb + s) * 128 + qi];
    l[s] = Pml[(pb + s) * 128 + 64 + qi];
    mstar = fmaxf(mstar, m[s]);
  }
  float w[SPLIT], denom = 0.f;
#pragma unroll
  for (int s = 0; s < SPLIT; ++s) { w[s] = __builtin_amdgcn_exp2f(m[s] - mstar); denom += w[s] * l[s]; }
  const float inv = 1.0f / denom;

  unsigned short vals[16];
#pragma unroll
  for (int j = 0; j < 16; ++j) {
    float a = 0.f;
#pragma unroll
    for (int s = 0; s < SPLIT; ++s)
      a += w[s] * Pacc[(pb + s) * 4096 + (size_t)(d0 + j) * 64 + qi];
    vals[j] = f2bf(a * inv);
  }
  unsigned short* xp = Xb + ((size_t)(b * Sc) + qt * 64 + qi) * Dc + h * DKc + d0;
  *(us8*)xp = *(us8*)&vals[0];
  *(us8*)(xp + 8) = *(us8*)&vals[8];
}

extern "C" void kernel_launch(void* const* d_in, const int* in_sizes, int n_in,
                              void* d_out, int out_size, void* d_ws, size_t ws_size,
                              hipStream_t stream)
{
  const float* query = (const float*)d_in[0];
  const float* key_  = (const float*)d_in[1];
  const float* value = (const float*)d_in[2];
  const float* gprob = (const float*)d_in[3];
  const int*   mask  = (const int*)d_in[4];
  const float* Wq = (const float*)d_in[5];
  const float* bq = (const float*)d_in[6];
  const float* Wk = (const float*)d_in[7];
  const float* bk = (const float*)d_in[8];
  const float* Wv = (const float*)d_in[9];
  const float* bv = (const float*)d_in[10];
  const float* Wo = (const float*)d_in[11];
  const float* bo = (const float*)d_in[12];
  float* out = (float*)d_out;

  const size_t elems = (size_t)Bc * Sc * Dc;     // 2 Mi
  const size_t gelems = (size_t)Bc * Sc * Sc;    // 8 Mi
  const size_t welems = (size_t)Dc * Dc;         // 256 Ki

  char* base = (char*)d_ws;
  unsigned short* Qb = (unsigned short*)(base);                    // 4 MB
  unsigned short* Kb = Qb + elems;                                 // 4 MB
  unsigned short* Vt = Kb + elems;                                 // 4 MB
  unsigned short* Xb = Vt + elems;                                 // 4 MB
  unsigned short* Gp = Xb + elems;                                 // 16.8 MB (permuted masked bf16 g, LSB=allowed)
  unsigned short* Wqb = Gp + gelems;                               // 4 x 0.5 MB bf16 weights
  unsigned short* Wkb = Wqb + welems;
  unsigned short* Wvb = Wkb + welems;
  unsigned short* Wob = Wvb + welems;
  float* Pacc = (float*)(Wob + welems);                            // 16.8 MB
  float* Pml  = Pacc + (size_t)(Bc * Hc) * 32 * SPLIT * 4096;      // 0.5 MB

  // fused prepass: permuted g_eff + weight conversions
  PArgs pa;
  pa.g = gprob; pa.m = mask; pa.gp = Gp;
  pa.wsrc[0] = Wq; pa.wdst[0] = Wqb;
  pa.wsrc[1] = Wk; pa.wdst[1] = Wkb;
  pa.wsrc[2] = Wv; pa.wdst[2] = Wvb;
  pa.wsrc[3] = Wo; pa.wdst[3] = Wob;
  hipLaunchKernelGGL(prepass, dim3(2080), dim3(256), 0, stream, pa);

  // fused Q/K/V projections: fp32 A reg-staged, Q output pre-scaled by CSC
  GArgs gq;
  gq.A[0] = (const void*)query; gq.W[0] = Wqb; gq.bias[0] = bq; gq.C[0] = (void*)Qb; gq.mode[0] = 0; gq.osc[0] = CSC;
  gq.A[1] = (const void*)key_;  gq.W[1] = Wkb; gq.bias[1] = bk; gq.C[1] = (void*)Kb; gq.mode[1] = 0; gq.osc[1] = 1.0f;
  gq.A[2] = (const void*)value; gq.W[2] = Wvb; gq.bias[2] = bv; gq.C[2] = (void*)Vt; gq.mode[2] = 1; gq.osc[2] = 1.0f;
  hipLaunchKernelGGL((gemm_bn64<1>), dim3(32, 8, 3), dim3(256), 0, stream, gq);

  dim3 ga(Bc * Hc, Sc / 64, SPLIT);
  hipLaunchKernelGGL(attn_split, ga, dim3(256), 0, stream, Qb, Kb, Vt, Gp, Pacc, Pml);
  hipLaunchKernelGGL(attn_reduce, dim3(Bc * Hc * 32), dim3(256), 0, stream, Pacc, Pml, Xb);

  // output projection: bf16 A via global_load_lds
  GArgs go;
  go.A[0] = (const void*)Xb; go.W[0] = Wob; go.bias[0] = bo; go.C[0] = (void*)out; go.mode[0] = 2; go.osc[0] = 1.0f;
  go.A[1] = go.A[0]; go.W[1] = go.W[0]; go.bias[1] = go.bias[0]; go.C[1] = go.C[0]; go.mode[1] = 2; go.osc[1] = 1.0f;
  go.A[2] = go.A[0]; go.W[2] = go.W[0]; go.bias[2] = go.bias[0]; go.C[2] = go.C[0]; go.mode[2] = 2; go.osc[2] = 1.0f;
  hipLaunchKernelGGL((gemm_bn64<0>), dim3(32, 8, 1), dim3(256), 0, stream, go);
}